// Round 2
// baseline (4676.931 us; speedup 1.0000x reference)
//
#include <hip/hip_runtime.h>
#include <hip/hip_bf16.h>
#include <stdint.h>
#include <stddef.h>

// ---------------------------------------------------------------------------
// GRUEncoder: x[256,512,25,3] f32 -> 2-layer GRU(H=256) -> fc(hT) -> [256,256] f32
//
// Time-chunked pipeline (chunk = TC steps, TC chosen from ws_size, cap 128):
//   cast_x  : x -> xb fp16 [T*B, 96] (t-major rows, K padded 75->96)
//   cast_w  : weights -> fp16; bias0/1 = b_ih + (r,z part of b_hh)
//   per chunk c:
//     gemm  : xgc = xb[c] @ W_ih0^T + bias0     (fp16 MFMA, f32 acc)
//     scan  : layer-0 recurrence (W_hh0 register-resident) -> out0c, h0s
//     gemm  : xgc = out0c @ W_ih1^T + bias1     (xgc buffer reused)
//     scan  : layer-1 recurrence -> h1s
//   cast_h  : h1s f32 -> hT fp16
//   gemm    : d_out = hT @ fc_W^T + fc_b (f32 out)
//
// h carried in f32 registers within a chunk and f32 globals across chunks ->
// chunking is numerically identical to a single 512-step scan.
// ---------------------------------------------------------------------------

typedef _Float16 f16;
typedef _Float16 f16x8 __attribute__((ext_vector_type(8)));
typedef float    f32x4 __attribute__((ext_vector_type(4)));

#define B_      256
#define T_      512
#define H_      256
#define G_      768      // 3*H
#define IN_RAW  75
#define KX      96       // padded input K
#define MROWS   (T_*B_)  // 131072

__device__ __forceinline__ float sigm(float x){ return 1.f/(1.f+__expf(-x)); }
__device__ __forceinline__ float tanh_(float x){ return 1.f - 2.f/(1.f+__expf(2.f*x)); }

// --------------------------------------------------------------------------
// cast_x: x[b][t][j] (f32) -> xb[t*256+b][96] (fp16, j>=75 zero)
// --------------------------------------------------------------------------
__global__ __launch_bounds__(256) void cast_x(const float* __restrict__ x,
                                              f16* __restrict__ xb){
  int idx = blockIdx.x*256 + threadIdx.x;        // grid*256 == 131072*96 exact
  int row = idx / KX;
  int j   = idx - row*KX;
  int t   = row >> 8;        // row = t*256 + b
  int b   = row & 255;
  float v = (j < IN_RAW) ? x[((size_t)b*T_ + t)*IN_RAW + j] : 0.f;
  xb[idx] = (f16)v;
}

// --------------------------------------------------------------------------
// cast_w: all weight casts + fused biases. grid*256 == 730624 exact.
// --------------------------------------------------------------------------
__global__ __launch_bounds__(256) void cast_w(
    const float* __restrict__ Wih0, const float* __restrict__ Whh0,
    const float* __restrict__ Wih1, const float* __restrict__ Whh1,
    const float* __restrict__ fcW,
    const float* __restrict__ bih0, const float* __restrict__ bhh0,
    const float* __restrict__ bih1, const float* __restrict__ bhh1,
    f16* __restrict__ W0h, f16* __restrict__ Whh0h, f16* __restrict__ Wih1h,
    f16* __restrict__ Whh1h, f16* __restrict__ fcWh,
    float* __restrict__ bias0, float* __restrict__ bias1){
  int i = blockIdx.x*256 + threadIdx.x;
  if (i < 73728){ int r = i/KX, j = i - r*KX;
    W0h[i] = (f16)((j < IN_RAW) ? Wih0[r*IN_RAW + j] : 0.f); return; }
  i -= 73728;
  if (i < 196608){ Whh0h[i] = (f16)Whh0[i]; return; } i -= 196608;
  if (i < 196608){ Wih1h[i] = (f16)Wih1[i]; return; } i -= 196608;
  if (i < 196608){ Whh1h[i] = (f16)Whh1[i]; return; } i -= 196608;
  if (i < 65536){ fcWh[i] = (f16)fcW[i]; return; } i -= 65536;
  if (i < 768){ bias0[i] = bih0[i] + (i < 512 ? bhh0[i] : 0.f); return; } i -= 768;
  if (i < 768){ bias1[i] = bih1[i] + (i < 512 ? bhh1[i] : 0.f); }
}

// --------------------------------------------------------------------------
// cast_h: h1s f32 [256*256] -> hT fp16
// --------------------------------------------------------------------------
__global__ __launch_bounds__(256) void cast_h(const float* __restrict__ hs,
                                              f16* __restrict__ hT){
  int i = blockIdx.x*256 + threadIdx.x;
  hT[i] = (f16)hs[i];
}

// --------------------------------------------------------------------------
// gemm_k: out[M,N] = A[M,K](fp16) @ W[N,K]^T(fp16) + bias.  No-LDS MFMA GEMM;
// W rows are L2-resident, A streamed. WG = 4 waves; wave owns WM=32 rows
// (2 A-frags) x BN cols -> 24 MFMA per 14 fragment loads.
// --------------------------------------------------------------------------
template<int K, int BN, bool OUTF32>
__global__ __launch_bounds__(256, 2) void gemm_k(const f16* __restrict__ A,
    const f16* __restrict__ W, const float* __restrict__ bias,
    void* __restrict__ outp, const int N){
  constexpr int NT = BN/16;
  const int tid  = threadIdx.x;
  const int wave = tid >> 6, lane = tid & 63;
  const int quad = lane >> 4, l16 = lane & 15;
  const long mbase = (long)blockIdx.x*128 + wave*32;
  const int  nbase = blockIdx.y*BN;
  f32x4 acc[2][NT] = {};
#pragma unroll 2
  for (int kc = 0; kc < K/32; ++kc){
    f16x8 a0 = *(const f16x8*)(A + (mbase +      l16)*K + kc*32 + quad*8);
    f16x8 a1 = *(const f16x8*)(A + (mbase + 16 + l16)*K + kc*32 + quad*8);
#pragma unroll
    for (int nt = 0; nt < NT; ++nt){
      f16x8 b = *(const f16x8*)(W + (long)(nbase + nt*16 + l16)*K + kc*32 + quad*8);
      acc[0][nt] = __builtin_amdgcn_mfma_f32_16x16x32_f16(a0, b, acc[0][nt], 0, 0, 0);
      acc[1][nt] = __builtin_amdgcn_mfma_f32_16x16x32_f16(a1, b, acc[1][nt], 0, 0, 0);
    }
  }
#pragma unroll
  for (int nt = 0; nt < NT; ++nt){
    const int col = nbase + nt*16 + l16;
    const float bv = bias[col];
#pragma unroll
    for (int af = 0; af < 2; ++af){
#pragma unroll
      for (int r = 0; r < 4; ++r){
        const long row = mbase + af*16 + quad*4 + r;   // D row = quad*4 + reg
        float v = acc[af][nt][r] + bv;
        if (OUTF32) ((float*)outp)[row*(long)N + col] = v;
        else        ((f16*)outp)[row*(long)N + col] = (f16)v;
      }
    }
  }
}

// --------------------------------------------------------------------------
// scan: TC steps of one GRU layer. 16 WGs x 512 thr (8 waves); WG owns batch
// rows [bx*16,+16). W_hh register-resident: wave w owns gate cols
// [w*32,+32) of r/z/n -> 2(s) x 3(gate) x 8(kc) f16x8 = 192 VGPR/lane.
// h f32 in registers; chunk boundaries via hstate (f32 global).
// hbuf fp16 pitch 264 (breaks 16-way ds_read_b128 bank conflict).
// xg tile double-buffered in LDS, next step prefetched through registers.
// --------------------------------------------------------------------------
__global__ __launch_bounds__(512, 1) void scan(const f16* __restrict__ xg,
    const f16* __restrict__ Whh, const float* __restrict__ bhh,
    float* __restrict__ hstate, f16* __restrict__ out0, const int TC){
  __shared__ f16 hbuf[16*264];
  __shared__ f16 xgb[2][16*G_];
  const int tid  = threadIdx.x;
  const int wave = tid >> 6, lane = tid & 63;
  const int quad = lane >> 4, l16 = lane & 15;
  const int b0   = blockIdx.x*16;

  // register-resident weights: B-frag = W[ncol][k], 8 consecutive k per lane
  f16x8 w[2][3][8];
#pragma unroll
  for (int s = 0; s < 2; ++s)
#pragma unroll
    for (int g = 0; g < 3; ++g){
      const int ncol = g*256 + wave*32 + s*16 + l16;
#pragma unroll
      for (int kc = 0; kc < 8; ++kc)
        w[s][g][kc] = *(const f16x8*)(Whh + (size_t)ncol*H_ + kc*32 + quad*8);
    }
  // n-gate hidden bias (stays inside r*(...) term) -> accumulator init
  float bn[2] = { bhh[512 + wave*32 + l16], bhh[512 + wave*32 + 16 + l16] };

  // h state: lane owns (m=quad*4+r, j=wave*32+s*16+l16); covers 16x256 exactly
  float h[2][4];
#pragma unroll
  for (int s = 0; s < 2; ++s)
#pragma unroll
    for (int r = 0; r < 4; ++r){
      const int m = quad*4 + r, j = wave*32 + s*16 + l16;
      float hv = hstate[(size_t)(b0 + m)*H_ + j];
      h[s][r] = hv;
      hbuf[m*264 + j] = (f16)hv;
    }

  // stage xg(t=0)
  {
    const uint4* gs = (const uint4*)(xg + (size_t)b0*G_);
    uint4 r0 = gs[tid*3+0], r1 = gs[tid*3+1], r2 = gs[tid*3+2];
    uint4* ld = (uint4*)&xgb[0][0];
    ld[tid*3+0] = r0; ld[tid*3+1] = r1; ld[tid*3+2] = r2;
  }
  __syncthreads();

  for (int t = 0; t < TC; ++t){
    const int pb = t & 1;
    const bool pre = (t+1 < TC);
    uint4 p0, p1, p2;
    if (pre){  // prefetch next step's xg tile (latency hidden across the step)
      const uint4* gs = (const uint4*)(xg + (size_t)(t+1)*(B_*G_) + (size_t)b0*G_);
      p0 = gs[tid*3+0]; p1 = gs[tid*3+1]; p2 = gs[tid*3+2];
    }
#pragma unroll
    for (int s = 0; s < 2; ++s){
      f32x4 aR = {0,0,0,0}, aZ = {0,0,0,0};
      f32x4 aN = {bn[s], bn[s], bn[s], bn[s]};
#pragma unroll
      for (int kc = 0; kc < 8; ++kc){
        f16x8 a = *(const f16x8*)(&hbuf[l16*264 + kc*32 + quad*8]);
        aR = __builtin_amdgcn_mfma_f32_16x16x32_f16(a, w[s][0][kc], aR, 0,0,0);
        aZ = __builtin_amdgcn_mfma_f32_16x16x32_f16(a, w[s][1][kc], aZ, 0,0,0);
        aN = __builtin_amdgcn_mfma_f32_16x16x32_f16(a, w[s][2][kc], aN, 0,0,0);
      }
      const int j = wave*32 + s*16 + l16;
#pragma unroll
      for (int r = 0; r < 4; ++r){
        const int m = quad*4 + r;
        float xr = (float)xgb[pb][m*G_ + j];
        float xz = (float)xgb[pb][m*G_ + 256 + j];
        float xn = (float)xgb[pb][m*G_ + 512 + j];
        float rg = sigm(xr + aR[r]);
        float zg = sigm(xz + aZ[r]);
        float ng = tanh_(xn + rg*aN[r]);
        h[s][r] = (1.f - zg)*ng + zg*h[s][r];
      }
    }
    __syncthreads();   // all reads of hbuf h(t-1) / xgb[pb] complete
#pragma unroll
    for (int s = 0; s < 2; ++s){
      const int j = wave*32 + s*16 + l16;
#pragma unroll
      for (int r = 0; r < 4; ++r)
        hbuf[(quad*4 + r)*264 + j] = (f16)h[s][r];
    }
    if (pre){
      uint4* ld = (uint4*)&xgb[pb^1][0];
      ld[tid*3+0] = p0; ld[tid*3+1] = p1; ld[tid*3+2] = p2;
    }
    __syncthreads();   // h(t) in hbuf, xg(t+1) staged
    if (out0){         // coalesced h(t) store via hbuf round-trip
      const int rl = tid >> 5, col = (tid & 31)*8;
      f16x8 v = *(const f16x8*)&hbuf[rl*264 + col];
      *(f16x8*)(out0 + ((size_t)t*B_ + b0 + rl)*H_ + col) = v;
    }
  }

#pragma unroll
  for (int s = 0; s < 2; ++s)
#pragma unroll
    for (int r = 0; r < 4; ++r)
      hstate[(size_t)(b0 + quad*4 + r)*H_ + wave*32 + s*16 + l16] = h[s][r];
}

// --------------------------------------------------------------------------
extern "C" void kernel_launch(void* const* d_in, const int* in_sizes, int n_in,
                              void* d_out, int out_size, void* d_ws, size_t ws_size,
                              hipStream_t stream){
  (void)in_sizes; (void)n_in; (void)out_size;
  const float* x    = (const float*)d_in[0];
  const float* Wih0 = (const float*)d_in[1];
  const float* Whh0 = (const float*)d_in[2];
  const float* bih0 = (const float*)d_in[3];
  const float* bhh0 = (const float*)d_in[4];
  const float* Wih1 = (const float*)d_in[5];
  const float* Whh1 = (const float*)d_in[6];
  const float* bih1 = (const float*)d_in[7];
  const float* bhh1 = (const float*)d_in[8];
  const float* fcW  = (const float*)d_in[9];
  const float* fcb  = (const float*)d_in[10];

  char* ws = (char*)d_ws;
  size_t off = 0;
  auto alloc = [&](size_t bytes) -> void* {
    void* p = ws + off; off += (bytes + 255) & ~(size_t)255; return p;
  };
  f16*   xb    = (f16*)  alloc((size_t)MROWS*KX*2);   // 25.2 MB
  f16*   W0h   = (f16*)  alloc((size_t)G_*KX*2);
  f16*   Whh0h = (f16*)  alloc((size_t)G_*H_*2);
  f16*   Wih1h = (f16*)  alloc((size_t)G_*H_*2);
  f16*   Whh1h = (f16*)  alloc((size_t)G_*H_*2);
  f16*   fcWh  = (f16*)  alloc((size_t)H_*H_*2);
  float* bias0 = (float*)alloc(G_*4);
  float* bias1 = (float*)alloc(G_*4);
  float* h0s   = (float*)alloc((size_t)B_*H_*4);      // h-state, both layers
  float* h1s   = (float*)alloc((size_t)B_*H_*4);      //   (adjacent: one memset)
  f16*   hTh   = (f16*)  alloc((size_t)B_*H_*2);
  const size_t fixed = off;

  // chunk size: largest TC in {128,64,32,16,8} fitting ws_size
  int TC = 128;
  while (TC > 8 && fixed + (size_t)TC*(393216 + 131072) + 1024 > ws_size) TC >>= 1;
  f16* xgc   = (f16*)alloc((size_t)TC*B_*G_*2);       // shared by both layers
  f16* out0c = (f16*)alloc((size_t)TC*B_*H_*2);
  const int nc = T_ / TC;

  hipMemsetAsync(h0s, 0, (size_t)B_*H_*4*2, stream);  // zero h0s+h1s (adjacent)
  hipLaunchKernelGGL(cast_x, dim3(49152), dim3(256), 0, stream, x, xb);
  hipLaunchKernelGGL(cast_w, dim3(2854), dim3(256), 0, stream,
                     Wih0, Whh0, Wih1, Whh1, fcW, bih0, bhh0, bih1, bhh1,
                     W0h, Whh0h, Wih1h, Whh1h, fcWh, bias0, bias1);

  for (int c = 0; c < nc; ++c){
    // xg = xb[c] @ W_ih0^T + bias0
    hipLaunchKernelGGL((gemm_k<96,192,false>), dim3(TC*2,4), dim3(256), 0, stream,
                       xb + (size_t)c*TC*B_*KX, W0h, bias0, (void*)xgc, G_);
    // layer-0 scan -> out0c, h0s
    hipLaunchKernelGGL(scan, dim3(16), dim3(512), 0, stream,
                       xgc, Whh0h, bhh0, h0s, out0c, TC);
    // xg = out0c @ W_ih1^T + bias1
    hipLaunchKernelGGL((gemm_k<256,192,false>), dim3(TC*2,4), dim3(256), 0, stream,
                       out0c, Wih1h, bias1, (void*)xgc, G_);
    // layer-1 scan -> h1s
    hipLaunchKernelGGL(scan, dim3(16), dim3(512), 0, stream,
                       xgc, Whh1h, bhh1, h1s, (f16*)nullptr, TC);
  }
  // embedding = hT @ fc_W^T + fc_b (f32 out)
  hipLaunchKernelGGL(cast_h, dim3(256), dim3(256), 0, stream, h1s, hTh);
  hipLaunchKernelGGL((gemm_k<256,64,true>), dim3(2,4), dim3(256), 0, stream,
                     hTh, fcWh, fcb, d_out, H_);
}